// Round 3
// baseline (112.211 us; speedup 1.0000x reference)
//
#include <hip/hip_runtime.h>

#define DD 128
#define KADJ 12
#define BN_TOTAL 12800

typedef float f32x4 __attribute__((ext_vector_type(4)));
typedef __bf16 bf16x8 __attribute__((ext_vector_type(8)));

__device__ __forceinline__ bf16x8 cvt8(f32x4 a, f32x4 b) {
    bf16x8 r;
    r[0] = (__bf16)a[0]; r[1] = (__bf16)a[1]; r[2] = (__bf16)a[2]; r[3] = (__bf16)a[3];
    r[4] = (__bf16)b[0]; r[5] = (__bf16)b[1]; r[6] = (__bf16)b[2]; r[7] = (__bf16)b[3];
    return r;
}

// ---- K0: w1[0:128][128] -> w1t[d][k] bf16 (32KB); w3[256][128] -> w3t[d][c] bf16 (64KB)
__global__ void k_prep(const float* __restrict__ w1, const float* __restrict__ w3,
                       __bf16* __restrict__ w1t, __bf16* __restrict__ w3t) {
    int b = blockIdx.x, t = threadIdx.x;
    if (b < 64) {
        int d = b * 2 + (t >> 7), k = t & 127;
        w1t[d * 128 + k] = (__bf16)w1[k * 128 + d];
    } else {
        int d = b - 64, c = t;
        w3t[d * 256 + c] = (__bf16)w3[c * 128 + d];
    }
}

// ---- K1: each wave handles 4 bn sequentially; no LDS, minimal shfl, att via
// ---- coalesced L2-hot adj re-read (lane = column). ----
__launch_bounds__(256, 4)
__global__ void k_att(const float* __restrict__ ave, const float* __restrict__ adj,
                      const float* __restrict__ wgt, const float* __restrict__ w1,
                      const float* __restrict__ w2, const __bf16* __restrict__ w1t,
                      float* __restrict__ att_out) {
    const int t = threadIdx.x;
    const int lane = t & 63;
    const int w = t >> 6;
    const int bn0 = blockIdx.x * 16 + w * 4;
    const int l = lane & 15, g = lane >> 4;

    // loop-invariant operands (L1-broadcast reads)
    float w1r[8], w2v[8];
    #pragma unroll
    for (int n = 0; n < 8; ++n) {
        w1r[n] = w1[128 * DD + n * 16 + l];   // w1 row 128 = concat'd wgt row
        w2v[n] = w2[n * 16 + l];
    }

    for (int i = 0; i < 4; ++i) {
        const int bn = bn0 + i;
        const float* avep = ave + (size_t)bn * DD;
        const float* adjp = adj + (size_t)bn * KADJ * DD;

        // --- A-frags: A[r][c] = ave[c]*adj[r][c], rows >=12 zero
        const bool rowok = (l < KADJ);
        const float* arow = adjp + (size_t)(rowok ? l : KADJ - 1) * DD;
        bf16x8 af[4];
        #pragma unroll
        for (int s = 0; s < 4; ++s) {
            int c = s * 32 + g * 8;
            f32x4 u0 = *reinterpret_cast<const f32x4*>(arow + c);
            f32x4 u1 = *reinterpret_cast<const f32x4*>(arow + c + 4);
            f32x4 e0 = *reinterpret_cast<const f32x4*>(avep + c);
            f32x4 e1 = *reinterpret_cast<const f32x4*>(avep + c + 4);
            if (!rowok) { u0 = f32x4{0.f,0.f,0.f,0.f}; u1 = f32x4{0.f,0.f,0.f,0.f}; }
            af[s] = cvt8(u0 * e0, u1 * e1);
        }

        // --- MFMA: C[16x128] = A @ w1t^T (B-frags from L1/L2-resident w1t)
        f32x4 acc[8];
        #pragma unroll
        for (int n = 0; n < 8; ++n) acc[n] = f32x4{0.f,0.f,0.f,0.f};
        #pragma unroll
        for (int s = 0; s < 4; ++s) {
            const __bf16* bp = w1t + (size_t)l * 128 + s * 32 + g * 8;
            #pragma unroll
            for (int n = 0; n < 8; ++n) {
                bf16x8 bfr = *reinterpret_cast<const bf16x8*>(bp + n * 2048);
                acc[n] = __builtin_amdgcn_mfma_f32_16x16x32_bf16(af[s], bfr, acc[n], 0, 0, 0);
            }
        }

        // --- rank-1 wgt column, leaky, dot w2. acc[n][j] = h[row g*4+j][col n*16+l]
        float wgtv[4];
        #pragma unroll
        for (int j = 0; j < 4; ++j) {
            int r = g * 4 + j;
            wgtv[j] = (r < KADJ) ? wgt[(size_t)bn * KADJ + r] : 0.f;
        }
        float p[4] = {0.f, 0.f, 0.f, 0.f};
        #pragma unroll
        for (int n = 0; n < 8; ++n) {
            #pragma unroll
            for (int j = 0; j < 4; ++j) {
                float h = fmaf(wgtv[j], w1r[n], acc[n][j]);
                h = h > 0.f ? h : 0.2f * h;
                p[j] = fmaf(h, w2v[n], p[j]);
            }
        }
        #pragma unroll
        for (int j = 0; j < 4; ++j) {
            p[j] += __shfl_xor(p[j], 1, 64);
            p[j] += __shfl_xor(p[j], 2, 64);
            p[j] += __shfl_xor(p[j], 4, 64);
            p[j] += __shfl_xor(p[j], 8, 64);
            if (g == 3) p[j] = -1e30f;          // pad rows 12..15 out of softmax
        }

        // gather: every lane gets all 16 scores (rows (g^m)*4+j)
        float q0[4], q1[4], q2[4];
        #pragma unroll
        for (int j = 0; j < 4; ++j) {
            q0[j] = __shfl_xor(p[j], 16, 64);
            q1[j] = __shfl_xor(p[j], 32, 64);
            q2[j] = __shfl_xor(q1[j], 16, 64);
        }
        float mx = -1e30f;
        #pragma unroll
        for (int j = 0; j < 4; ++j) {
            mx = fmaxf(mx, fmaxf(fmaxf(p[j], q0[j]), fmaxf(q1[j], q2[j])));
        }
        float ssum = 0.f;
        #pragma unroll
        for (int j = 0; j < 4; ++j) {
            ssum += __expf(p[j] - mx);  ssum += __expf(q0[j] - mx);
            ssum += __expf(q1[j] - mx); ssum += __expf(q2[j] - mx);
        }
        float inv = 1.f / ssum;

        // --- att: lanes = columns, adj rows re-read coalesced from L2
        float a0 = 0.f, a1 = 0.f;
        #pragma unroll
        for (int k = 0; k < KADJ; ++k) {
            int gk = k >> 2, j = k & 3;
            int d = gk ^ g;
            float sv = (d == 0) ? p[j] : (d == 1) ? q0[j] : (d == 2) ? q1[j] : q2[j];
            float alpha = __expf(sv - mx) * inv;
            a0 = fmaf(alpha, adjp[k * DD + lane], a0);
            a1 = fmaf(alpha, adjp[k * DD + 64 + lane], a1);
        }
        att_out[(size_t)bn * DD + lane] = a0;
        att_out[(size_t)bn * DD + 64 + lane] = a1;
    }
}

// ---- K2: out = relu([itm | att] @ w3) via MFMA; att read from own rows of d_out ----
__launch_bounds__(64)
__global__ void k_out(const float* __restrict__ itm, const float* att,
                      const __bf16* __restrict__ w3t, float* outp) {
    const int lane = threadIdx.x & 63;
    const int l = lane & 15, g = lane >> 4;
    const int R0 = blockIdx.x * 16;
    const int row = R0 + l;

    bf16x8 afr[8];
    const float* ip = itm + (size_t)row * DD;
    #pragma unroll
    for (int s = 0; s < 4; ++s) {
        int c = s * 32 + g * 8;
        f32x4 a0 = *reinterpret_cast<const f32x4*>(ip + c);
        f32x4 a1 = *reinterpret_cast<const f32x4*>(ip + c + 4);
        afr[s] = cvt8(a0, a1);
    }
    const float* ap = att + (size_t)row * DD;
    #pragma unroll
    for (int s = 0; s < 4; ++s) {
        int c = s * 32 + g * 8;
        f32x4 a0 = *reinterpret_cast<const f32x4*>(ap + c);
        f32x4 a1 = *reinterpret_cast<const f32x4*>(ap + c + 4);
        afr[4 + s] = cvt8(a0, a1);
    }

    f32x4 acc[8];
    #pragma unroll
    for (int n = 0; n < 8; ++n) acc[n] = f32x4{0.f,0.f,0.f,0.f};
    #pragma unroll
    for (int s = 0; s < 8; ++s) {
        const __bf16* bp = w3t + (size_t)l * 256 + s * 32 + g * 8;
        #pragma unroll
        for (int n = 0; n < 8; ++n) {
            bf16x8 bfr = *reinterpret_cast<const bf16x8*>(bp + n * 4096);
            acc[n] = __builtin_amdgcn_mfma_f32_16x16x32_bf16(afr[s], bfr, acc[n], 0, 0, 0);
        }
    }

    #pragma unroll
    for (int n = 0; n < 8; ++n) {
        #pragma unroll
        for (int j = 0; j < 4; ++j)
            outp[(size_t)(R0 + g * 4 + j) * DD + n * 16 + l] = fmaxf(acc[n][j], 0.f);
    }
}

extern "C" void kernel_launch(void* const* d_in, const int* in_sizes, int n_in,
                              void* d_out, int out_size, void* d_ws, size_t ws_size,
                              hipStream_t stream) {
    const float* itm = (const float*)d_in[1];
    const float* ave = (const float*)d_in[2];
    const float* adj = (const float*)d_in[3];
    const float* wgt = (const float*)d_in[4];
    const float* w1  = (const float*)d_in[5];
    const float* w2  = (const float*)d_in[6];
    const float* w3  = (const float*)d_in[7];
    float* outp = (float*)d_out;

    __bf16* w1t = (__bf16*)d_ws;                       // 128*128*2 = 32 KB
    __bf16* w3t = (__bf16*)((char*)d_ws + 32 * 1024);  // 128*256*2 = 64 KB

    k_prep<<<dim3(192), dim3(256), 0, stream>>>(w1, w3, w1t, w3t);
    k_att<<<dim3(BN_TOTAL / 16), dim3(256), 0, stream>>>(ave, adj, wgt, w1, w2, w1t, outp);
    k_out<<<dim3(BN_TOTAL / 16), dim3(64), 0, stream>>>(itm, outp, w3t, outp);
}

// Round 4
// 48.213 us; speedup vs baseline: 2.3274x; 2.3274x over previous
//
#include <hip/hip_runtime.h>

#define DD 128
#define KADJ 12
#define BN_TOTAL 12800

typedef float f32x4 __attribute__((ext_vector_type(4)));
typedef float f32x2 __attribute__((ext_vector_type(2)));
typedef __bf16 bf16x8 __attribute__((ext_vector_type(8)));
typedef __bf16 bf16x4 __attribute__((ext_vector_type(4)));
typedef unsigned int u32;

__device__ __forceinline__ bf16x8 cvt8(f32x4 a, f32x4 b) {
    bf16x8 r;
    r[0] = (__bf16)a[0]; r[1] = (__bf16)a[1]; r[2] = (__bf16)a[2]; r[3] = (__bf16)a[3];
    r[4] = (__bf16)b[0]; r[5] = (__bf16)b[1]; r[6] = (__bf16)b[2]; r[7] = (__bf16)b[3];
    return r;
}

__device__ __forceinline__ bf16x8 mul8(bf16x8 a, bf16x8 b) {
    bf16x8 r;
    #pragma unroll
    for (int i = 0; i < 8; ++i) r[i] = (__bf16)((float)a[i] * (float)b[i]);
    return r;
}

// ---- K0: shuffle w1 (0..127 rows) and w3 into MFMA B-fragment order, bf16 ----
// w1f[(n*4+ks)*512 + lane*8 + e] = w1[(ks*32 + (lane>>4)*8 + e)*128 + n*16 + (lane&15)]
// w3f[(n*8+ks)*512 + lane*8 + e] = w3[(ks*32 + (lane>>4)*8 + e)*128 + n*16 + (lane&15)]
__global__ void k_prep(const float* __restrict__ w1, const float* __restrict__ w3,
                       __bf16* __restrict__ w1f, __bf16* __restrict__ w3f) {
    int idx = blockIdx.x * 256 + threadIdx.x;   // 0..49151
    int lane = (idx >> 3) & 63, e = idx & 7;
    int l = lane & 15, gg = lane >> 4;
    if (idx < 16384) {
        int fi = idx >> 9, n = fi >> 2, ks = fi & 3;
        int k = ks * 32 + gg * 8 + e;
        w1f[idx] = (__bf16)w1[k * DD + n * 16 + l];
    } else {
        int j = idx - 16384;
        int fi = j >> 9, n = fi >> 3, ks = fi & 7;
        int k = ks * 32 + gg * 8 + e;
        w3f[j] = (__bf16)w3[k * DD + n * 16 + l];
    }
}

// ---- K1: streaming GEMM + softmax + att. Wave-local: 4 bn = 48 rows, no barriers ----
__launch_bounds__(256)
__global__ void k_att(const float* __restrict__ ave, const float* __restrict__ adj,
                      const float* __restrict__ wgt, const float* __restrict__ w1,
                      const float* __restrict__ w2, const __bf16* __restrict__ w1f,
                      float* __restrict__ att_out) {
    __shared__ unsigned char lds[54528];
    const int t = threadIdx.x;
    const int lane = t & 63;
    const int w = t >> 6;
    const int l = lane & 15, g = lane >> 4;
    const int bn0 = blockIdx.x * 16 + w * 4;
    const size_t R = (size_t)bn0 * KADJ;          // global A-row base for this wave

    unsigned char* adjb = lds + w * 12288;                    // 48 rows x 256B, swizzled
    unsigned char* aveb = lds + 49152 + w * 1088;             // 4 rows x 272B
    float* sco = (float*)(lds + 53504 + w * 256);             // 48 scores

    // ---- stage 48 adj rows -> bf16 LDS, swizzled (coalesced nontemporal reads) ----
    {
        const float* src = adj + R * DD;
        const int r = lane >> 5;            // 0..1
        const int c4 = (lane & 31) * 4;     // float col
        const int u = c4 >> 3, bo = (c4 & 7) * 2;
        #pragma unroll
        for (int i = 0; i < 24; ++i) {
            int row = i * 2 + r;
            f32x4 v = __builtin_nontemporal_load(
                reinterpret_cast<const f32x4*>(src + (size_t)row * DD + c4));
            bf16x4 bv;
            bv[0] = (__bf16)v[0]; bv[1] = (__bf16)v[1];
            bv[2] = (__bf16)v[2]; bv[3] = (__bf16)v[3];
            *reinterpret_cast<bf16x4*>(adjb + row * 256 + ((u ^ (row & 15)) << 4) + bo) = bv;
        }
    }
    // ---- stage 4 ave rows -> bf16 LDS (stride 272B breaks bank aliasing) ----
    {
        const int a = lane >> 4;            // 0..3
        const int c8 = (lane & 15) * 8;
        const float* src = ave + (size_t)(bn0 + a) * DD + c8;
        f32x4 v0 = *reinterpret_cast<const f32x4*>(src);
        f32x4 v1 = *reinterpret_cast<const f32x4*>(src + 4);
        *reinterpret_cast<bf16x8*>(aveb + a * 272 + c8 * 2) = cvt8(v0, v1);
    }

    // loop-invariant operands
    float w1r[8], w2v[8];
    #pragma unroll
    for (int n = 0; n < 8; ++n) {
        w1r[n] = w1[128 * DD + n * 16 + l];   // w1 row 128 = concat'd wgt row
        w2v[n] = w2[n * 16 + l];
    }

    // ---- 3 row-tiles of 16 (48 real rows, no padding) ----
    #pragma unroll
    for (int rt = 0; rt < 3; ++rt) {
        const int lr = rt * 16 + l;
        const int arow = lr >= 36 ? 3 : lr >= 24 ? 2 : lr >= 12 ? 1 : 0;
        f32x4 acc[8];
        #pragma unroll
        for (int n = 0; n < 8; ++n) acc[n] = f32x4{0.f, 0.f, 0.f, 0.f};
        #pragma unroll
        for (int ks = 0; ks < 4; ++ks) {
            bf16x8 adjf = *reinterpret_cast<const bf16x8*>(
                adjb + lr * 256 + (((ks * 4 + g) ^ (lr & 15)) << 4));
            bf16x8 avef = *reinterpret_cast<const bf16x8*>(
                aveb + arow * 272 + ks * 64 + g * 16);
            bf16x8 af = mul8(adjf, avef);
            const __bf16* bp = w1f + ((size_t)ks * 64 + lane) * 8;   // coalesced 1KB/wave
            #pragma unroll
            for (int n = 0; n < 8; ++n) {
                bf16x8 bfr = *reinterpret_cast<const bf16x8*>(bp + (size_t)n * 2048);
                acc[n] = __builtin_amdgcn_mfma_f32_16x16x32_bf16(af, bfr, acc[n], 0, 0, 0);
            }
        }
        // epilogue: rank-1 wgt column, leaky-relu, dot w2; reduce over the 16 l-lanes
        float wv[4];
        #pragma unroll
        for (int j = 0; j < 4; ++j)
            wv[j] = wgt[R + rt * 16 + g * 4 + j];
        float p[4] = {0.f, 0.f, 0.f, 0.f};
        #pragma unroll
        for (int n = 0; n < 8; ++n) {
            #pragma unroll
            for (int j = 0; j < 4; ++j) {
                float h = fmaf(wv[j], w1r[n], acc[n][j]);
                h = h > 0.f ? h : 0.2f * h;
                p[j] = fmaf(h, w2v[n], p[j]);
            }
        }
        #pragma unroll
        for (int j = 0; j < 4; ++j) {
            p[j] += __shfl_xor(p[j], 1, 64);
            p[j] += __shfl_xor(p[j], 2, 64);
            p[j] += __shfl_xor(p[j], 4, 64);
            p[j] += __shfl_xor(p[j], 8, 64);
        }
        if (l == 0)
            *reinterpret_cast<f32x4*>(&sco[rt * 16 + g * 4]) = f32x4{p[0], p[1], p[2], p[3]};
    }

    // ---- softmax + att per bn; adj columns re-read from LDS (conflict-free b32) ----
    #pragma unroll
    for (int b = 0; b < 4; ++b) {
        float s[KADJ];
        float mx = -1e30f;
        #pragma unroll
        for (int k = 0; k < KADJ; ++k) { s[k] = sco[b * 12 + k]; mx = fmaxf(mx, s[k]); }
        float sum = 0.f;
        #pragma unroll
        for (int k = 0; k < KADJ; ++k) { s[k] = __expf(s[k] - mx); sum += s[k]; }
        float inv = 1.f / sum;
        float a0 = 0.f, a1 = 0.f;
        #pragma unroll
        for (int k = 0; k < KADJ; ++k) {
            int row = b * 12 + k;
            u32 pk = *reinterpret_cast<const u32*>(
                adjb + row * 256 + ((((lane >> 2) ^ (row & 15))) << 4) + (lane & 3) * 4);
            float alpha = s[k] * inv;
            float e0 = __builtin_bit_cast(float, pk << 16);
            float e1 = __builtin_bit_cast(float, pk & 0xFFFF0000u);
            a0 = fmaf(alpha, e0, a0);
            a1 = fmaf(alpha, e1, a1);
        }
        *reinterpret_cast<f32x2*>(att_out + (size_t)(bn0 + b) * DD + lane * 2) = f32x2{a0, a1};
    }
}

// ---- K2: out = relu([itm | att] @ w3) via MFMA; B-frags coalesced from w3f ----
__launch_bounds__(64)
__global__ void k_out(const float* __restrict__ itm, const float* att,
                      const __bf16* __restrict__ w3f, float* outp) {
    const int lane = threadIdx.x & 63;
    const int l = lane & 15, g = lane >> 4;
    const int R0 = blockIdx.x * 16;
    const int row = R0 + l;

    bf16x8 afr[8];
    const float* ip = itm + (size_t)row * DD;
    #pragma unroll
    for (int s = 0; s < 4; ++s) {
        int c = s * 32 + g * 8;
        f32x4 a0 = *reinterpret_cast<const f32x4*>(ip + c);
        f32x4 a1 = *reinterpret_cast<const f32x4*>(ip + c + 4);
        afr[s] = cvt8(a0, a1);
    }
    const float* ap = att + (size_t)row * DD;
    #pragma unroll
    for (int s = 0; s < 4; ++s) {
        int c = s * 32 + g * 8;
        f32x4 a0 = *reinterpret_cast<const f32x4*>(ap + c);
        f32x4 a1 = *reinterpret_cast<const f32x4*>(ap + c + 4);
        afr[4 + s] = cvt8(a0, a1);
    }

    f32x4 acc[8];
    #pragma unroll
    for (int n = 0; n < 8; ++n) acc[n] = f32x4{0.f, 0.f, 0.f, 0.f};
    #pragma unroll
    for (int s = 0; s < 8; ++s) {
        const __bf16* bp = w3f + ((size_t)s * 64 + lane) * 8;    // coalesced 1KB/wave
        #pragma unroll
        for (int n = 0; n < 8; ++n) {
            bf16x8 bfr = *reinterpret_cast<const bf16x8*>(bp + (size_t)n * 4096);
            acc[n] = __builtin_amdgcn_mfma_f32_16x16x32_bf16(afr[s], bfr, acc[n], 0, 0, 0);
        }
    }

    #pragma unroll
    for (int n = 0; n < 8; ++n) {
        #pragma unroll
        for (int j = 0; j < 4; ++j)
            outp[(size_t)(R0 + g * 4 + j) * DD + n * 16 + l] = fmaxf(acc[n][j], 0.f);
    }
}

extern "C" void kernel_launch(void* const* d_in, const int* in_sizes, int n_in,
                              void* d_out, int out_size, void* d_ws, size_t ws_size,
                              hipStream_t stream) {
    const float* itm = (const float*)d_in[1];
    const float* ave = (const float*)d_in[2];
    const float* adj = (const float*)d_in[3];
    const float* wgt = (const float*)d_in[4];
    const float* w1  = (const float*)d_in[5];
    const float* w2  = (const float*)d_in[6];
    const float* w3  = (const float*)d_in[7];
    float* outp = (float*)d_out;

    __bf16* w1f = (__bf16*)d_ws;                       // 32 KB, fragment-ordered
    __bf16* w3f = (__bf16*)((char*)d_ws + 32 * 1024);  // 64 KB, fragment-ordered

    k_prep<<<dim3(192), dim3(256), 0, stream>>>(w1, w3, w1f, w3f);
    k_att<<<dim3(BN_TOTAL / 16), dim3(256), 0, stream>>>(ave, adj, wgt, w1, w2, w1f, outp);
    k_out<<<dim3(BN_TOTAL / 16), dim3(64), 0, stream>>>(itm, outp, w3f, outp);
}